// Round 1
// baseline (1131.237 us; speedup 1.0000x reference)
//
#include <hip/hip_runtime.h>

// GraphConvolutionSparse forward:
//   xw  = X_sparse @ W        (COO scatter-add, atomics into d_ws)
//   out = A_sparse @ xw       (COO gather + scatter-add, atomics into d_out)
//   out = relu(out)
//
// Shapes: N=100000 nodes, D_IN=512, D_OUT=128, NNZ_X=800000, N_E=1600000.
// d_ws holds the [N, 128] fp32 intermediate (51.2 MB).

#define DOUT 128

// Kernel 1: xw[row, d] += val * W[col, d]   (one 128-thread group per nnz)
__global__ void spmm_xw_kernel(const float* __restrict__ x_vals,
                               const int* __restrict__ x_rows,
                               const int* __restrict__ x_cols,
                               const float* __restrict__ W,
                               float* __restrict__ xw,
                               int nnz) {
    long long t = (long long)blockIdx.x * blockDim.x + threadIdx.x;
    int i = (int)(t >> 7);   // nnz index
    int d = (int)(t & 127);  // output channel
    if (i >= nnz) return;
    float v = x_vals[i];
    int r = x_rows[i];
    int c = x_cols[i];
    atomicAdd(&xw[(long long)r * DOUT + d], v * W[(long long)c * DOUT + d]);
}

// Kernel 2: out[row, d] += aval * xw[col, d]   (one 128-thread group per edge)
__global__ void spmm_adj_kernel(const float* __restrict__ adj_vals,
                                const int* __restrict__ adj_rows,
                                const int* __restrict__ adj_cols,
                                const float* __restrict__ xw,
                                float* __restrict__ out,
                                int n_e) {
    long long t = (long long)blockIdx.x * blockDim.x + threadIdx.x;
    int e = (int)(t >> 7);
    int d = (int)(t & 127);
    if (e >= n_e) return;
    float v = adj_vals[e];
    int r = adj_rows[e];
    int c = adj_cols[e];
    atomicAdd(&out[(long long)r * DOUT + d], v * xw[(long long)c * DOUT + d]);
}

// Kernel 3: relu in place (vectorized float4)
__global__ void relu_kernel(float4* __restrict__ out, int n4) {
    int i = blockIdx.x * blockDim.x + threadIdx.x;
    if (i >= n4) return;
    float4 v = out[i];
    v.x = fmaxf(v.x, 0.0f);
    v.y = fmaxf(v.y, 0.0f);
    v.z = fmaxf(v.z, 0.0f);
    v.w = fmaxf(v.w, 0.0f);
    out[i] = v;
}

extern "C" void kernel_launch(void* const* d_in, const int* in_sizes, int n_in,
                              void* d_out, int out_size, void* d_ws, size_t ws_size,
                              hipStream_t stream) {
    const float* x_vals   = (const float*)d_in[0];
    const int*   x_rows   = (const int*)d_in[1];
    const int*   x_cols   = (const int*)d_in[2];
    const float* adj_vals = (const float*)d_in[3];
    const int*   adj_rows = (const int*)d_in[4];
    const int*   adj_cols = (const int*)d_in[5];
    const float* W        = (const float*)d_in[6];
    float* out = (float*)d_out;
    float* xw  = (float*)d_ws;   // [N, 128] fp32 = out_size elements

    const int nnz_x = in_sizes[0];
    const int n_e   = in_sizes[3];
    // out_size = N * 128; xw has the same element count.

    // Zero the accumulation buffers (harness poisons them with 0xAA).
    hipMemsetAsync(xw, 0, (size_t)out_size * sizeof(float), stream);
    hipMemsetAsync(out, 0, (size_t)out_size * sizeof(float), stream);

    // Kernel 1: 128 threads per nnz, 2 nnz per 256-thread block.
    {
        long long total = (long long)nnz_x * DOUT;
        int blocks = (int)((total + 255) / 256);
        spmm_xw_kernel<<<blocks, 256, 0, stream>>>(x_vals, x_rows, x_cols, W, xw, nnz_x);
    }

    // Kernel 2: 128 threads per edge.
    {
        long long total = (long long)n_e * DOUT;
        int blocks = (int)((total + 255) / 256);
        spmm_adj_kernel<<<blocks, 256, 0, stream>>>(adj_vals, adj_rows, adj_cols, xw, out, n_e);
    }

    // Kernel 3: relu in place.
    {
        int n4 = out_size / 4;
        int blocks = (n4 + 255) / 256;
        relu_kernel<<<blocks, 256, 0, stream>>>((float4*)out, n4);
    }
}

// Round 2
// 672.241 us; speedup vs baseline: 1.6828x; 1.6828x over previous
//
#include <hip/hip_runtime.h>

// GraphConvolutionSparse forward, CSR-ized on device each call:
//   1. histogram rows of X and A           (atomicAdd on 400 KB counters, L2-resident)
//   2. exclusive scan both histograms      (single-block shfl scan, grid=2)
//   3. scatter (col,val) pairs into CSR order
//   4. xw[r,:]  = sum val * W[col,:]       (wave per row, register accumulate, 1 write)
//   5. out[r,:] = relu(sum aval * xw[col,:])  (wave per row, relu fused)
//
// Shapes: N=100000, D_IN=512, D_OUT=128, NNZ_X=800000, N_E=1600000.
// Replaces round-0's 1.2 GB of atomic write traffic with ~102 MB of plain writes.

#define DOUT 128

static inline size_t align_up(size_t x, size_t a) { return (x + a - 1) & ~(a - 1); }

// ---------------- sort phase ----------------

__global__ void hist_kernel(const int* __restrict__ rows, int n, int* __restrict__ cnt) {
    int i = blockIdx.x * blockDim.x + threadIdx.x;
    if (i < n) atomicAdd(&cnt[rows[i]], 1);
}

// Single-block exclusive scan per array; grid=2 (block 0: X hist, block 1: A hist).
// Writes start[] (exclusive offsets, start[n]=total) and cursor[]=start copy.
__global__ void scan_kernel(const int* __restrict__ cnt_x, int* __restrict__ start_x, int* __restrict__ cur_x,
                            const int* __restrict__ cnt_a, int* __restrict__ start_a, int* __restrict__ cur_a,
                            int n) {
    const int* cnt; int* start; int* cur;
    if (blockIdx.x == 0) { cnt = cnt_x; start = start_x; cur = cur_x; }
    else                 { cnt = cnt_a; start = start_a; cur = cur_a; }

    __shared__ int wsum[16];
    __shared__ int woff[16];
    __shared__ int carry_s;
    __shared__ int chunk_tot;
    int tid = threadIdx.x, lane = tid & 63, wid = tid >> 6;
    if (tid == 0) carry_s = 0;
    __syncthreads();

    for (int base = 0; base < n; base += 1024) {
        int i = base + tid;
        int v = (i < n) ? cnt[i] : 0;
        int incl = v;
        #pragma unroll
        for (int off = 1; off < 64; off <<= 1) {
            int up = __shfl_up(incl, off, 64);
            if (lane >= off) incl += up;
        }
        if (lane == 63) wsum[wid] = incl;
        __syncthreads();
        if (wid == 0 && lane < 16) {
            int s = wsum[lane];
            int is = s;
            #pragma unroll
            for (int off = 1; off < 16; off <<= 1) {
                int up = __shfl_up(is, off, 16);
                if (lane >= off) is += up;
            }
            woff[lane] = is - s;            // exclusive wave offset
            if (lane == 15) chunk_tot = is; // chunk total
        }
        __syncthreads();
        int excl = incl - v + woff[wid] + carry_s;
        if (i < n) { start[i] = excl; cur[i] = excl; }
        __syncthreads();
        if (tid == 0) carry_s += chunk_tot;
        __syncthreads();
    }
    if (threadIdx.x == 0) start[n] = carry_s;
}

__global__ void scatter_kernel(const int* __restrict__ rows, const int* __restrict__ cols,
                               const float* __restrict__ vals, int n,
                               int* __restrict__ cur, int2* __restrict__ sorted) {
    int i = blockIdx.x * blockDim.x + threadIdx.x;
    if (i < n) {
        int p = atomicAdd(&cur[rows[i]], 1);
        sorted[p] = make_int2(cols[i], __float_as_int(vals[i]));
    }
}

// ---------------- gather phase (wave per row, float2 per lane) ----------------

__global__ void row_xw_kernel(const int* __restrict__ x_start, const int2* __restrict__ xs,
                              const float* __restrict__ W, float* __restrict__ xw, int n) {
    int r = (int)((blockIdx.x * (long long)blockDim.x + threadIdx.x) >> 6);
    if (r >= n) return;
    int lane = threadIdx.x & 63;
    int s = x_start[r], e = x_start[r + 1];
    float ax = 0.f, ay = 0.f;
    for (int i = s; i < e; ++i) {
        int2 cv = xs[i];                       // wave-uniform 8B broadcast load
        float v = __int_as_float(cv.y);
        float2 wv = ((const float2*)(W + (size_t)cv.x * DOUT))[lane];
        ax += v * wv.x;
        ay += v * wv.y;
    }
    ((float2*)(xw + (size_t)r * DOUT))[lane] = make_float2(ax, ay);
}

__global__ void row_adj_kernel(const int* __restrict__ a_start, const int2* __restrict__ as,
                               const float* __restrict__ xw, float* __restrict__ out, int n) {
    int r = (int)((blockIdx.x * (long long)blockDim.x + threadIdx.x) >> 6);
    if (r >= n) return;
    int lane = threadIdx.x & 63;
    int s = a_start[r], e = a_start[r + 1];
    float ax = 0.f, ay = 0.f;
    for (int i = s; i < e; ++i) {
        int2 cv = as[i];
        float v = __int_as_float(cv.y);
        float2 hv = ((const float2*)(xw + (size_t)cv.x * DOUT))[lane];
        ax += v * hv.x;
        ay += v * hv.y;
    }
    ((float2*)(out + (size_t)r * DOUT))[lane] = make_float2(fmaxf(ax, 0.f), fmaxf(ay, 0.f));
}

// ---------------- round-0 fallback (atomic scatter) if ws too small ----------------

__global__ void spmm_xw_atomic(const float* __restrict__ x_vals, const int* __restrict__ x_rows,
                               const int* __restrict__ x_cols, const float* __restrict__ W,
                               float* __restrict__ xw, int nnz) {
    long long t = (long long)blockIdx.x * blockDim.x + threadIdx.x;
    int i = (int)(t >> 7), d = (int)(t & 127);
    if (i >= nnz) return;
    atomicAdd(&xw[(long long)x_rows[i] * DOUT + d], x_vals[i] * W[(long long)x_cols[i] * DOUT + d]);
}
__global__ void spmm_adj_atomic(const float* __restrict__ adj_vals, const int* __restrict__ adj_rows,
                                const int* __restrict__ adj_cols, const float* __restrict__ xw,
                                float* __restrict__ out, int n_e) {
    long long t = (long long)blockIdx.x * blockDim.x + threadIdx.x;
    int e = (int)(t >> 7), d = (int)(t & 127);
    if (e >= n_e) return;
    atomicAdd(&out[(long long)adj_rows[e] * DOUT + d], adj_vals[e] * xw[(long long)adj_cols[e] * DOUT + d]);
}
__global__ void relu_kernel(float4* __restrict__ out, int n4) {
    int i = blockIdx.x * blockDim.x + threadIdx.x;
    if (i >= n4) return;
    float4 v = out[i];
    v.x = fmaxf(v.x, 0.f); v.y = fmaxf(v.y, 0.f);
    v.z = fmaxf(v.z, 0.f); v.w = fmaxf(v.w, 0.f);
    out[i] = v;
}

extern "C" void kernel_launch(void* const* d_in, const int* in_sizes, int n_in,
                              void* d_out, int out_size, void* d_ws, size_t ws_size,
                              hipStream_t stream) {
    const float* x_vals   = (const float*)d_in[0];
    const int*   x_rows   = (const int*)d_in[1];
    const int*   x_cols   = (const int*)d_in[2];
    const float* adj_vals = (const float*)d_in[3];
    const int*   adj_rows = (const int*)d_in[4];
    const int*   adj_cols = (const int*)d_in[5];
    const float* W        = (const float*)d_in[6];
    float* out = (float*)d_out;

    const int nnz_x = in_sizes[0];
    const int n_e   = in_sizes[3];
    const int N     = out_size / DOUT;

    // Workspace layout
    char* ws = (char*)d_ws;
    size_t off = 0;
    size_t xw_off      = off; off = align_up(off + (size_t)N * DOUT * sizeof(float), 128);
    size_t xstart_off  = off; off = align_up(off + (size_t)(N + 1) * sizeof(int), 128);
    size_t xcur_off    = off; off = align_up(off + (size_t)N * sizeof(int), 128);
    size_t astart_off  = off; off = align_up(off + (size_t)(N + 1) * sizeof(int), 128);
    size_t acur_off    = off; off = align_up(off + (size_t)N * sizeof(int), 128);
    size_t xsort_off   = off; off = align_up(off + (size_t)nnz_x * sizeof(int2), 128);
    size_t asort_off   = off; off = align_up(off + (size_t)n_e * sizeof(int2), 128);
    size_t needed = off;

    float* xw = (float*)(ws + xw_off);

    if (ws_size >= needed) {
        int*  x_start = (int*)(ws + xstart_off);
        int*  x_cur   = (int*)(ws + xcur_off);
        int*  a_start = (int*)(ws + astart_off);
        int*  a_cur   = (int*)(ws + acur_off);
        int2* x_sort  = (int2*)(ws + xsort_off);
        int2* a_sort  = (int2*)(ws + asort_off);

        // 1. zero histograms (counts accumulated in the cursor arrays)
        hipMemsetAsync(x_cur, 0, (size_t)N * sizeof(int), stream);
        hipMemsetAsync(a_cur, 0, (size_t)N * sizeof(int), stream);

        // 2. histograms
        hist_kernel<<<(nnz_x + 255) / 256, 256, 0, stream>>>(x_rows, nnz_x, x_cur);
        hist_kernel<<<(n_e + 255) / 256, 256, 0, stream>>>(adj_rows, n_e, a_cur);

        // 3. exclusive scans (block 0: X, block 1: A); rewrites cursors to start offsets
        scan_kernel<<<2, 1024, 0, stream>>>(x_cur, x_start, x_cur, a_cur, a_start, a_cur, N);

        // 4. scatter into CSR order
        scatter_kernel<<<(nnz_x + 255) / 256, 256, 0, stream>>>(x_rows, x_cols, x_vals, nnz_x, x_cur, x_sort);
        scatter_kernel<<<(n_e + 255) / 256, 256, 0, stream>>>(adj_rows, adj_cols, adj_vals, n_e, a_cur, a_sort);

        // 5. row-gather SpMMs (wave per row; every row written, no pre-zero needed)
        int blocks = (N * 64 + 255) / 256;  // 4 rows per 256-thread block
        row_xw_kernel<<<blocks, 256, 0, stream>>>(x_start, x_sort, W, xw, N);
        row_adj_kernel<<<blocks, 256, 0, stream>>>(a_start, a_sort, xw, out, N);
    } else {
        // Fallback: round-0 atomic path (needs only xw in ws)
        hipMemsetAsync(xw, 0, (size_t)out_size * sizeof(float), stream);
        hipMemsetAsync(out, 0, (size_t)out_size * sizeof(float), stream);
        long long t1 = (long long)nnz_x * DOUT;
        spmm_xw_atomic<<<(int)((t1 + 255) / 256), 256, 0, stream>>>(x_vals, x_rows, x_cols, W, xw, nnz_x);
        long long t2 = (long long)n_e * DOUT;
        spmm_adj_atomic<<<(int)((t2 + 255) / 256), 256, 0, stream>>>(adj_vals, adj_rows, adj_cols, xw, out, n_e);
        relu_kernel<<<(out_size / 4 + 255) / 256, 256, 0, stream>>>((float4*)out, out_size / 4);
    }
}

// Round 3
// 515.904 us; speedup vs baseline: 2.1927x; 1.3030x over previous
//
#include <hip/hip_runtime.h>
#include <hip/hip_fp16.h>

// GraphConvolutionSparse forward, CSR-ized on device each call.
// Round-2 changes: xw stored fp16 (halves row_adj gather bytes),
// multiblock scan (kills the serial single-block scan), fused hist/scatter
// launches (8 dispatches total).
//
// Pipeline:
//   1. memset cnt_x|cnt_a (one 800 KB memset)
//   2. hist2: histogram both row arrays
//   3. sum256 / scan_partials / scan_final: two-level exclusive scan -> start,cur
//   4. scatter2: (col,val) int2 pairs into CSR order for both matrices
//   5. row_xw: wave/row, fp32 acc, write xw as fp16      [N x 128]
//   6. row_adj: wave/row, fp16 gather, fp32 acc, fused relu, fp32 out

#define DOUT 128

static inline size_t align_up(size_t x, size_t a) { return (x + a - 1) & ~(a - 1); }

__device__ inline int wave_incl_scan(int v, int lane) {
    #pragma unroll
    for (int off = 1; off < 64; off <<= 1) {
        int up = __shfl_up(v, off, 64);
        if (lane >= off) v += up;
    }
    return v;
}

// ---- histogram both arrays in one launch ----
__global__ void hist2_kernel(const int* __restrict__ xr, int nx,
                             const int* __restrict__ ar, int na,
                             int* __restrict__ cx, int* __restrict__ ca) {
    int i = blockIdx.x * blockDim.x + threadIdx.x;
    if (i < nx) {
        atomicAdd(&cx[xr[i]], 1);
    } else {
        int j = i - nx;
        if (j < na) atomicAdd(&ca[ar[j]], 1);
    }
}

// ---- two-level exclusive scan (grid.y selects X/A) ----
// S1: per-256-chunk sums
__global__ void sum256_kernel(const int* __restrict__ cx, const int* __restrict__ ca,
                              int* __restrict__ px, int* __restrict__ pa, int n) {
    const int* cnt = blockIdx.y ? ca : cx;
    int* part = blockIdx.y ? pa : px;
    int tid = threadIdx.x, lane = tid & 63, wid = tid >> 6;
    int i = blockIdx.x * 256 + tid;
    int v = (i < n) ? cnt[i] : 0;
    #pragma unroll
    for (int off = 32; off > 0; off >>= 1) v += __shfl_xor(v, off, 64);
    __shared__ int wsum[4];
    if (lane == 0) wsum[wid] = v;
    __syncthreads();
    if (tid == 0) part[blockIdx.x] = wsum[0] + wsum[1] + wsum[2] + wsum[3];
}

// S2: exclusive scan of partials in place (nb <= 1024); writes start[n]=total
__global__ void scan_partials_kernel(int* __restrict__ px, int* __restrict__ pa,
                                     int* __restrict__ sx, int* __restrict__ sa,
                                     int nb, int n) {
    int* p = blockIdx.y ? pa : px;
    int* start = blockIdx.y ? sa : sx;
    __shared__ int wsum[16];
    int tid = threadIdx.x, lane = tid & 63, wid = tid >> 6;
    int v = (tid < nb) ? p[tid] : 0;
    int incl = wave_incl_scan(v, lane);
    if (lane == 63) wsum[wid] = incl;
    __syncthreads();
    if (tid < 16) {
        int s = wsum[tid];
        int is = s;
        #pragma unroll
        for (int off = 1; off < 16; off <<= 1) {
            int up = __shfl_up(is, off, 64);
            if (tid >= off) is += up;
        }
        wsum[tid] = is - s;
    }
    __syncthreads();
    int excl = incl - v + wsum[wid];
    if (tid < nb) p[tid] = excl;
    if (tid == nb - 1) start[n] = excl + v;   // grand total
}

// S3: rescan each chunk + block offset -> start[], cur[]
__global__ void scan_final_kernel(const int* __restrict__ cx, const int* __restrict__ px,
                                  int* __restrict__ sx, int* __restrict__ curx,
                                  const int* __restrict__ ca, const int* __restrict__ pa,
                                  int* __restrict__ sa, int* __restrict__ cura, int n) {
    const int* cnt; const int* part; int* start; int* cur;
    if (blockIdx.y == 0) { cnt = cx; part = px; start = sx; cur = curx; }
    else                 { cnt = ca; part = pa; start = sa; cur = cura; }
    int tid = threadIdx.x, lane = tid & 63, wid = tid >> 6;
    int i = blockIdx.x * 256 + tid;
    int v = (i < n) ? cnt[i] : 0;
    __shared__ int wsum[4];
    int incl = wave_incl_scan(v, lane);
    if (lane == 63) wsum[wid] = incl;
    __syncthreads();
    if (tid < 4) {
        int s = wsum[tid];
        int is = s;
        #pragma unroll
        for (int off = 1; off < 4; off <<= 1) {
            int up = __shfl_up(is, off, 64);
            if (tid >= off) is += up;
        }
        wsum[tid] = is - s;
    }
    __syncthreads();
    int s = part[blockIdx.x] + incl - v + wsum[wid];
    if (i < n) { start[i] = s; cur[i] = s; }
}

// ---- scatter both arrays into CSR order in one launch ----
__global__ void scatter2_kernel(const int* __restrict__ xr, const int* __restrict__ xc,
                                const float* __restrict__ xv, int nx,
                                const int* __restrict__ ar, const int* __restrict__ ac,
                                const float* __restrict__ av, int na,
                                int* __restrict__ curx, int* __restrict__ cura,
                                int2* __restrict__ xs, int2* __restrict__ as) {
    int i = blockIdx.x * blockDim.x + threadIdx.x;
    if (i < nx) {
        int p = atomicAdd(&curx[xr[i]], 1);
        xs[p] = make_int2(xc[i], __float_as_int(xv[i]));
    } else {
        int j = i - nx;
        if (j < na) {
            int p = atomicAdd(&cura[ar[j]], 1);
            as[p] = make_int2(ac[j], __float_as_int(av[j]));
        }
    }
}

// ---- gather phase: wave per row ----
__global__ void row_xw_kernel(const int* __restrict__ x_start, const int2* __restrict__ xs,
                              const float* __restrict__ W, __half2* __restrict__ xwh, int n) {
    int r = (int)((blockIdx.x * (long long)blockDim.x + threadIdx.x) >> 6);
    if (r >= n) return;
    int lane = threadIdx.x & 63;
    int s = x_start[r], e = x_start[r + 1];
    float ax = 0.f, ay = 0.f;
    int i = s;
    for (; i + 1 < e; i += 2) {
        int2 c0 = xs[i], c1 = xs[i + 1];
        float2 w0 = ((const float2*)(W + (size_t)c0.x * DOUT))[lane];
        float2 w1 = ((const float2*)(W + (size_t)c1.x * DOUT))[lane];
        float v0 = __int_as_float(c0.y), v1 = __int_as_float(c1.y);
        ax += v0 * w0.x + v1 * w1.x;
        ay += v0 * w0.y + v1 * w1.y;
    }
    if (i < e) {
        int2 c0 = xs[i];
        float2 w0 = ((const float2*)(W + (size_t)c0.x * DOUT))[lane];
        float v0 = __int_as_float(c0.y);
        ax += v0 * w0.x;
        ay += v0 * w0.y;
    }
    xwh[(size_t)r * 64 + lane] = __float22half2_rn(make_float2(ax, ay));
}

__global__ void row_adj_kernel(const int* __restrict__ a_start, const int2* __restrict__ as,
                               const __half2* __restrict__ xwh, float* __restrict__ out, int n) {
    int r = (int)((blockIdx.x * (long long)blockDim.x + threadIdx.x) >> 6);
    if (r >= n) return;
    int lane = threadIdx.x & 63;
    int s = a_start[r], e = a_start[r + 1];
    float ax = 0.f, ay = 0.f;
    int i = s;
    for (; i + 1 < e; i += 2) {
        int2 c0 = as[i], c1 = as[i + 1];
        __half2 h0 = xwh[(size_t)c0.x * 64 + lane];
        __half2 h1 = xwh[(size_t)c1.x * 64 + lane];
        float v0 = __int_as_float(c0.y), v1 = __int_as_float(c1.y);
        float2 f0 = __half22float2(h0), f1 = __half22float2(h1);
        ax += v0 * f0.x + v1 * f1.x;
        ay += v0 * f0.y + v1 * f1.y;
    }
    if (i < e) {
        int2 c0 = as[i];
        __half2 h0 = xwh[(size_t)c0.x * 64 + lane];
        float v0 = __int_as_float(c0.y);
        float2 f0 = __half22float2(h0);
        ax += v0 * f0.x;
        ay += v0 * f0.y;
    }
    ((float2*)(out + (size_t)r * DOUT))[lane] = make_float2(fmaxf(ax, 0.f), fmaxf(ay, 0.f));
}

// ---- fallback (round-0 atomic path) if ws too small ----
__global__ void spmm_xw_atomic(const float* __restrict__ x_vals, const int* __restrict__ x_rows,
                               const int* __restrict__ x_cols, const float* __restrict__ W,
                               float* __restrict__ xw, int nnz) {
    long long t = (long long)blockIdx.x * blockDim.x + threadIdx.x;
    int i = (int)(t >> 7), d = (int)(t & 127);
    if (i >= nnz) return;
    atomicAdd(&xw[(long long)x_rows[i] * DOUT + d], x_vals[i] * W[(long long)x_cols[i] * DOUT + d]);
}
__global__ void spmm_adj_atomic(const float* __restrict__ adj_vals, const int* __restrict__ adj_rows,
                                const int* __restrict__ adj_cols, const float* __restrict__ xw,
                                float* __restrict__ out, int n_e) {
    long long t = (long long)blockIdx.x * blockDim.x + threadIdx.x;
    int e = (int)(t >> 7), d = (int)(t & 127);
    if (e >= n_e) return;
    atomicAdd(&out[(long long)adj_rows[e] * DOUT + d], adj_vals[e] * xw[(long long)adj_cols[e] * DOUT + d]);
}
__global__ void relu_kernel(float4* __restrict__ out, int n4) {
    int i = blockIdx.x * blockDim.x + threadIdx.x;
    if (i >= n4) return;
    float4 v = out[i];
    v.x = fmaxf(v.x, 0.f); v.y = fmaxf(v.y, 0.f);
    v.z = fmaxf(v.z, 0.f); v.w = fmaxf(v.w, 0.f);
    out[i] = v;
}

extern "C" void kernel_launch(void* const* d_in, const int* in_sizes, int n_in,
                              void* d_out, int out_size, void* d_ws, size_t ws_size,
                              hipStream_t stream) {
    const float* x_vals   = (const float*)d_in[0];
    const int*   x_rows   = (const int*)d_in[1];
    const int*   x_cols   = (const int*)d_in[2];
    const float* adj_vals = (const float*)d_in[3];
    const int*   adj_rows = (const int*)d_in[4];
    const int*   adj_cols = (const int*)d_in[5];
    const float* W        = (const float*)d_in[6];
    float* out = (float*)d_out;

    const int nnz_x = in_sizes[0];
    const int n_e   = in_sizes[3];
    const int N     = out_size / DOUT;
    const int nb    = (N + 255) / 256;   // scan chunks (must be <= 1024)

    // Workspace layout
    char* ws = (char*)d_ws;
    size_t off = 0;
    size_t xw_off     = off; off = align_up(off + (size_t)N * DOUT * sizeof(__half), 128);
    size_t cntx_off   = off; off += (size_t)N * sizeof(int);          // cnt_x | cnt_a adjacent
    size_t cnta_off   = off; off = align_up(off + (size_t)N * sizeof(int), 128);
    size_t sx_off     = off; off = align_up(off + (size_t)(N + 1) * sizeof(int), 128);
    size_t sa_off     = off; off = align_up(off + (size_t)(N + 1) * sizeof(int), 128);
    size_t curx_off   = off; off = align_up(off + (size_t)N * sizeof(int), 128);
    size_t cura_off   = off; off = align_up(off + (size_t)N * sizeof(int), 128);
    size_t px_off     = off; off = align_up(off + (size_t)nb * sizeof(int), 128);
    size_t pa_off     = off; off = align_up(off + (size_t)nb * sizeof(int), 128);
    size_t xsort_off  = off; off = align_up(off + (size_t)nnz_x * sizeof(int2), 128);
    size_t asort_off  = off; off = align_up(off + (size_t)n_e * sizeof(int2), 128);
    size_t needed = off;

    if (ws_size >= needed && nb <= 1024) {
        __half2* xwh   = (__half2*)(ws + xw_off);
        int*  cnt_x    = (int*)(ws + cntx_off);
        int*  cnt_a    = (int*)(ws + cnta_off);
        int*  sx       = (int*)(ws + sx_off);
        int*  sa       = (int*)(ws + sa_off);
        int*  cur_x    = (int*)(ws + curx_off);
        int*  cur_a    = (int*)(ws + cura_off);
        int*  px       = (int*)(ws + px_off);
        int*  pa       = (int*)(ws + pa_off);
        int2* x_sort   = (int2*)(ws + xsort_off);
        int2* a_sort   = (int2*)(ws + asort_off);

        // 1. zero both histograms with one memset (they're adjacent)
        hipMemsetAsync(cnt_x, 0, 2 * (size_t)N * sizeof(int), stream);

        // 2. fused histogram
        int tot = nnz_x + n_e;
        hist2_kernel<<<(tot + 255) / 256, 256, 0, stream>>>(x_rows, nnz_x, adj_rows, n_e, cnt_x, cnt_a);

        // 3. two-level exclusive scan
        sum256_kernel<<<dim3(nb, 2), 256, 0, stream>>>(cnt_x, cnt_a, px, pa, N);
        scan_partials_kernel<<<dim3(1, 2), 1024, 0, stream>>>(px, pa, sx, sa, nb, N);
        scan_final_kernel<<<dim3(nb, 2), 256, 0, stream>>>(cnt_x, px, sx, cur_x, cnt_a, pa, sa, cur_a, N);

        // 4. fused scatter into CSR order
        scatter2_kernel<<<(tot + 255) / 256, 256, 0, stream>>>(x_rows, x_cols, x_vals, nnz_x,
                                                               adj_rows, adj_cols, adj_vals, n_e,
                                                               cur_x, cur_a, x_sort, a_sort);

        // 5/6. row-gather SpMMs (wave per row)
        int blocks = (N * 64 + 255) / 256;
        row_xw_kernel<<<blocks, 256, 0, stream>>>(sx, x_sort, W, xwh, N);
        row_adj_kernel<<<blocks, 256, 0, stream>>>(sa, a_sort, xwh, out, N);
    } else {
        // Fallback: atomic scatter path (fp32 xw in ws)
        float* xw = (float*)ws;
        hipMemsetAsync(xw, 0, (size_t)out_size * sizeof(float), stream);
        hipMemsetAsync(out, 0, (size_t)out_size * sizeof(float), stream);
        long long t1 = (long long)nnz_x * DOUT;
        spmm_xw_atomic<<<(int)((t1 + 255) / 256), 256, 0, stream>>>(x_vals, x_rows, x_cols, W, xw, nnz_x);
        long long t2 = (long long)n_e * DOUT;
        spmm_adj_atomic<<<(int)((t2 + 255) / 256), 256, 0, stream>>>(adj_vals, adj_rows, adj_cols, xw, out, n_e);
        relu_kernel<<<(out_size / 4 + 255) / 256, 256, 0, stream>>>((float4*)out, out_size / 4);
    }
}

// Round 4
// 414.469 us; speedup vs baseline: 2.7294x; 1.2447x over previous
//
#include <hip/hip_runtime.h>
#include <hip/hip_fp16.h>

// GraphConvolutionSparse forward. Round-4 structure: coarse-bucket sort
// (128 rows/bucket -> scatter front fits L2, no line churn), fine per-row
// sort fused into the consumer kernels via an LDS permutation.
//
// Pipeline (7 dispatches):
//   1. memset coarse counters (8 KB)
//   2. hist_coarse: LDS-aggregated bucket histogram of both matrices
//   3. scan_nb: exclusive scan of 782 buckets (grid=2), writes base+cursor
//   4. bucket_scatter x2: block-reserved scatter of packed (row_lo|col, val)
//      into bucket-contiguous stage arrays (runs merge in L2)
//   5. consumer_xw: block/bucket: LDS hist+scan+rank -> perm; wave-per-row
//      register accumulate of W rows; write xw fp16
//   6. consumer_adj: same, gathering xw fp16; fused relu; fp32 out

#define DOUT 128
#define RB 128            // rows per bucket
#define RB_BITS 7
#define NBMAX 1024        // max buckets (supports N <= 131072, matches packing)
#define CAP 8192          // max payloads per bucket on the fast path
#define COLMASK 131071    // low 17 bits

static inline size_t align_up(size_t x, size_t a) { return (x + a - 1) & ~(a - 1); }

__device__ inline int wave_incl_scan(int v, int lane) {
    #pragma unroll
    for (int off = 1; off < 64; off <<= 1) {
        int up = __shfl_up(v, off, 64);
        if (lane >= off) v += up;
    }
    return v;
}

// ---- 2. coarse histogram, both matrices, LDS-aggregated ----
__global__ __launch_bounds__(256) void hist_coarse(const int* __restrict__ xr, int nx,
                                                   const int* __restrict__ ar, int na,
                                                   int* __restrict__ cx, int* __restrict__ ca) {
    __shared__ int h[2 * NBMAX];
    for (int i = threadIdx.x; i < 2 * NBMAX; i += 256) h[i] = 0;
    __syncthreads();
    int base = blockIdx.x * 4096;
    int tot = nx + na;
    #pragma unroll
    for (int k = 0; k < 16; ++k) {
        int i = base + k * 256 + threadIdx.x;
        if (i < tot) {
            if (i < nx) atomicAdd(&h[xr[i] >> RB_BITS], 1);
            else        atomicAdd(&h[NBMAX + (ar[i - nx] >> RB_BITS)], 1);
        }
    }
    __syncthreads();
    for (int i = threadIdx.x; i < 2 * NBMAX; i += 256) {
        int c = h[i];
        if (c) {
            if (i < NBMAX) atomicAdd(&cx[i], c);
            else           atomicAdd(&ca[i - NBMAX], c);
        }
    }
}

// ---- 3. exclusive scan of nb (<=1024) bucket counts; grid=2 picks matrix ----
__global__ __launch_bounds__(1024) void scan_nb(const int* __restrict__ cx, const int* __restrict__ ca,
                                                int* __restrict__ bx, int* __restrict__ ba,
                                                int* __restrict__ curx, int* __restrict__ cura, int nb) {
    const int* c = blockIdx.x ? ca : cx;
    int* bs  = blockIdx.x ? ba : bx;
    int* cur = blockIdx.x ? cura : curx;
    __shared__ int wsum[16];
    int tid = threadIdx.x, lane = tid & 63, wid = tid >> 6;
    int v = (tid < nb) ? c[tid] : 0;
    int incl = wave_incl_scan(v, lane);
    if (lane == 63) wsum[wid] = incl;
    __syncthreads();
    if (tid < 16) {
        int s = wsum[tid];
        int is = s;
        #pragma unroll
        for (int off = 1; off < 16; off <<= 1) {
            int up = __shfl_up(is, off, 64);
            if (tid >= off) is += up;
        }
        wsum[tid] = is - s;
    }
    __syncthreads();
    int excl = incl - v + wsum[wid];
    if (tid < nb) { bs[tid] = excl; cur[tid] = excl; }
    if (tid == nb - 1) bs[nb] = excl + v;
}

// ---- 4. bucket scatter with block-aggregated reservations ----
__global__ __launch_bounds__(512) void bucket_scatter(const int* __restrict__ rows, const int* __restrict__ cols,
                                                      const float* __restrict__ vals, int n,
                                                      int* __restrict__ gcur, int2* __restrict__ stage, int nb) {
    __shared__ int h[NBMAX];
    __shared__ int bcur[NBMAX];
    for (int i = threadIdx.x; i < nb; i += 512) h[i] = 0;
    __syncthreads();
    int base = blockIdx.x * 4096;
    int rr[8]; int cc[8]; float vv[8];
    #pragma unroll
    for (int k = 0; k < 8; ++k) {
        int i = base + k * 512 + threadIdx.x;
        rr[k] = -1;
        if (i < n) {
            rr[k] = rows[i]; cc[k] = cols[i]; vv[k] = vals[i];
            atomicAdd(&h[rr[k] >> RB_BITS], 1);
        }
    }
    __syncthreads();
    for (int b = threadIdx.x; b < nb; b += 512) {
        int c = h[b];
        bcur[b] = c ? atomicAdd(&gcur[b], c) : 0;
    }
    __syncthreads();
    #pragma unroll
    for (int k = 0; k < 8; ++k) {
        if (rr[k] >= 0) {
            int b = rr[k] >> RB_BITS;
            int p = atomicAdd(&bcur[b], 1);
            stage[p] = make_int2(((rr[k] & (RB - 1)) << 17) | cc[k], __float_as_int(vv[k]));
        }
    }
}

// ---- 5/6. consumers: block per bucket, LDS perm, wave per row ----
__global__ __launch_bounds__(256) void consumer_xw(const int* __restrict__ bx, const int2* __restrict__ stage,
                                                   const float* __restrict__ W, __half2* __restrict__ xwh, int N) {
    __shared__ unsigned short perm[CAP];
    __shared__ int hoff[RB + 1];
    __shared__ int curs[RB];
    __shared__ int w0s;
    int b = blockIdx.x;
    int s = bx[b], e = bx[b + 1];
    int cnt = e - s;
    int tid = threadIdx.x, lane = tid & 63, wid = tid >> 6;
    bool fast = (cnt <= CAP);
    if (tid < RB) curs[tid] = 0;
    __syncthreads();
    if (fast) {
        for (int i = tid; i < cnt; i += 256)
            atomicAdd(&curs[(stage[s + i].x >> 17) & (RB - 1)], 1);
    }
    __syncthreads();
    {   // exclusive scan of the 128 counts
        int v = (tid < RB) ? curs[tid] : 0;
        int incl = wave_incl_scan(v, lane);
        if (tid == 63) w0s = incl;
        __syncthreads();
        if (tid < RB) {
            int excl = incl - v + (wid == 1 ? w0s : 0);
            hoff[tid] = excl;
            curs[tid] = excl;
            if (tid == RB - 1) hoff[RB] = excl + v;
        }
        __syncthreads();
    }
    if (fast) {
        for (int i = tid; i < cnt; i += 256) {
            int r = (stage[s + i].x >> 17) & (RB - 1);
            perm[atomicAdd(&curs[r], 1)] = (unsigned short)i;
        }
    }
    __syncthreads();
    int row0 = b << RB_BITS;
    for (int r = wid; r < RB; r += 4) {
        int grow = row0 + r;
        if (grow >= N) continue;
        float ax = 0.f, ay = 0.f;
        if (fast) {
            int j = hoff[r], o1 = hoff[r + 1];
            for (; j + 1 < o1; j += 2) {
                int2 c0 = stage[s + perm[j]];
                int2 c1 = stage[s + perm[j + 1]];
                float2 w0 = ((const float2*)(W + ((size_t)(c0.x & COLMASK) << 7)))[lane];
                float2 w1 = ((const float2*)(W + ((size_t)(c1.x & COLMASK) << 7)))[lane];
                float v0 = __int_as_float(c0.y), v1 = __int_as_float(c1.y);
                ax += v0 * w0.x + v1 * w1.x;
                ay += v0 * w0.y + v1 * w1.y;
            }
            if (j < o1) {
                int2 c0 = stage[s + perm[j]];
                float2 w0 = ((const float2*)(W + ((size_t)(c0.x & COLMASK) << 7)))[lane];
                float v0 = __int_as_float(c0.y);
                ax += v0 * w0.x; ay += v0 * w0.y;
            }
        } else {
            for (int j = 0; j < cnt; ++j) {
                int2 c0 = stage[s + j];
                if (((c0.x >> 17) & (RB - 1)) == r) {
                    float2 w0 = ((const float2*)(W + ((size_t)(c0.x & COLMASK) << 7)))[lane];
                    float v0 = __int_as_float(c0.y);
                    ax += v0 * w0.x; ay += v0 * w0.y;
                }
            }
        }
        xwh[((size_t)grow << 6) + lane] = __float22half2_rn(make_float2(ax, ay));
    }
}

__global__ __launch_bounds__(256) void consumer_adj(const int* __restrict__ ba, const int2* __restrict__ stage,
                                                    const __half2* __restrict__ xwh, float* __restrict__ out, int N) {
    __shared__ unsigned short perm[CAP];
    __shared__ int hoff[RB + 1];
    __shared__ int curs[RB];
    __shared__ int w0s;
    int b = blockIdx.x;
    int s = ba[b], e = ba[b + 1];
    int cnt = e - s;
    int tid = threadIdx.x, lane = tid & 63, wid = tid >> 6;
    bool fast = (cnt <= CAP);
    if (tid < RB) curs[tid] = 0;
    __syncthreads();
    if (fast) {
        for (int i = tid; i < cnt; i += 256)
            atomicAdd(&curs[(stage[s + i].x >> 17) & (RB - 1)], 1);
    }
    __syncthreads();
    {
        int v = (tid < RB) ? curs[tid] : 0;
        int incl = wave_incl_scan(v, lane);
        if (tid == 63) w0s = incl;
        __syncthreads();
        if (tid < RB) {
            int excl = incl - v + (wid == 1 ? w0s : 0);
            hoff[tid] = excl;
            curs[tid] = excl;
            if (tid == RB - 1) hoff[RB] = excl + v;
        }
        __syncthreads();
    }
    if (fast) {
        for (int i = tid; i < cnt; i += 256) {
            int r = (stage[s + i].x >> 17) & (RB - 1);
            perm[atomicAdd(&curs[r], 1)] = (unsigned short)i;
        }
    }
    __syncthreads();
    int row0 = b << RB_BITS;
    for (int r = wid; r < RB; r += 4) {
        int grow = row0 + r;
        if (grow >= N) continue;
        float ax = 0.f, ay = 0.f;
        if (fast) {
            int j = hoff[r], o1 = hoff[r + 1];
            for (; j + 1 < o1; j += 2) {
                int2 c0 = stage[s + perm[j]];
                int2 c1 = stage[s + perm[j + 1]];
                float2 h0 = __half22float2(xwh[((size_t)(c0.x & COLMASK) << 6) + lane]);
                float2 h1 = __half22float2(xwh[((size_t)(c1.x & COLMASK) << 6) + lane]);
                float v0 = __int_as_float(c0.y), v1 = __int_as_float(c1.y);
                ax += v0 * h0.x + v1 * h1.x;
                ay += v0 * h0.y + v1 * h1.y;
            }
            if (j < o1) {
                int2 c0 = stage[s + perm[j]];
                float2 h0 = __half22float2(xwh[((size_t)(c0.x & COLMASK) << 6) + lane]);
                float v0 = __int_as_float(c0.y);
                ax += v0 * h0.x; ay += v0 * h0.y;
            }
        } else {
            for (int j = 0; j < cnt; ++j) {
                int2 c0 = stage[s + j];
                if (((c0.x >> 17) & (RB - 1)) == r) {
                    float2 h0 = __half22float2(xwh[((size_t)(c0.x & COLMASK) << 6) + lane]);
                    float v0 = __int_as_float(c0.y);
                    ax += v0 * h0.x; ay += v0 * h0.y;
                }
            }
        }
        ((float2*)(out + (size_t)grow * DOUT))[lane] = make_float2(fmaxf(ax, 0.f), fmaxf(ay, 0.f));
    }
}

// ---- fallback (atomic scatter) for oversized N / undersized ws ----
__global__ void spmm_xw_atomic(const float* __restrict__ x_vals, const int* __restrict__ x_rows,
                               const int* __restrict__ x_cols, const float* __restrict__ W,
                               float* __restrict__ xw, int nnz) {
    long long t = (long long)blockIdx.x * blockDim.x + threadIdx.x;
    int i = (int)(t >> 7), d = (int)(t & 127);
    if (i >= nnz) return;
    atomicAdd(&xw[(long long)x_rows[i] * DOUT + d], x_vals[i] * W[(long long)x_cols[i] * DOUT + d]);
}
__global__ void spmm_adj_atomic(const float* __restrict__ adj_vals, const int* __restrict__ adj_rows,
                                const int* __restrict__ adj_cols, const float* __restrict__ xw,
                                float* __restrict__ out, int n_e) {
    long long t = (long long)blockIdx.x * blockDim.x + threadIdx.x;
    int e = (int)(t >> 7), d = (int)(t & 127);
    if (e >= n_e) return;
    atomicAdd(&out[(long long)adj_rows[e] * DOUT + d], adj_vals[e] * xw[(long long)adj_cols[e] * DOUT + d]);
}
__global__ void relu_kernel(float4* __restrict__ out, int n4) {
    int i = blockIdx.x * blockDim.x + threadIdx.x;
    if (i >= n4) return;
    float4 v = out[i];
    v.x = fmaxf(v.x, 0.f); v.y = fmaxf(v.y, 0.f);
    v.z = fmaxf(v.z, 0.f); v.w = fmaxf(v.w, 0.f);
    out[i] = v;
}

extern "C" void kernel_launch(void* const* d_in, const int* in_sizes, int n_in,
                              void* d_out, int out_size, void* d_ws, size_t ws_size,
                              hipStream_t stream) {
    const float* x_vals   = (const float*)d_in[0];
    const int*   x_rows   = (const int*)d_in[1];
    const int*   x_cols   = (const int*)d_in[2];
    const float* adj_vals = (const float*)d_in[3];
    const int*   adj_rows = (const int*)d_in[4];
    const int*   adj_cols = (const int*)d_in[5];
    const float* W        = (const float*)d_in[6];
    float* out = (float*)d_out;

    const int nnz_x = in_sizes[0];
    const int n_e   = in_sizes[3];
    const int N     = out_size / DOUT;
    const int nb    = (N + RB - 1) / RB;

    // Workspace layout
    char* ws = (char*)d_ws;
    size_t off = 0;
    size_t xw_off    = off; off = align_up(off + (size_t)N * DOUT * sizeof(__half), 128);
    size_t cx_off    = off; off += (size_t)NBMAX * sizeof(int);       // cx | ca adjacent
    size_t ca_off    = off; off = align_up(off + (size_t)NBMAX * sizeof(int), 128);
    size_t bx_off    = off; off = align_up(off + (size_t)(NBMAX + 1) * sizeof(int), 128);
    size_t baoff     = off; off = align_up(off + (size_t)(NBMAX + 1) * sizeof(int), 128);
    size_t curx_off  = off; off = align_up(off + (size_t)NBMAX * sizeof(int), 128);
    size_t cura_off  = off; off = align_up(off + (size_t)NBMAX * sizeof(int), 128);
    size_t sx_off    = off; off = align_up(off + (size_t)nnz_x * sizeof(int2), 128);
    size_t sa_off    = off; off = align_up(off + (size_t)n_e * sizeof(int2), 128);
    size_t needed = off;

    if (ws_size >= needed && nb <= NBMAX && N <= (COLMASK + 1)) {
        __half2* xwh  = (__half2*)(ws + xw_off);
        int*  cx      = (int*)(ws + cx_off);
        int*  ca      = (int*)(ws + ca_off);
        int*  bx      = (int*)(ws + bx_off);
        int*  ba      = (int*)(ws + baoff);
        int*  curx    = (int*)(ws + curx_off);
        int*  cura    = (int*)(ws + cura_off);
        int2* stage_x = (int2*)(ws + sx_off);
        int2* stage_a = (int2*)(ws + sa_off);

        // 1. zero coarse counters (adjacent -> one memset)
        hipMemsetAsync(cx, 0, 2 * (size_t)NBMAX * sizeof(int), stream);

        // 2. coarse histogram of both matrices
        int tot = nnz_x + n_e;
        hist_coarse<<<(tot + 4095) / 4096, 256, 0, stream>>>(x_rows, nnz_x, adj_rows, n_e, cx, ca);

        // 3. bucket scan (grid=2: X, A)
        scan_nb<<<2, 1024, 0, stream>>>(cx, ca, bx, ba, curx, cura, nb);

        // 4. bucket scatters
        bucket_scatter<<<(nnz_x + 4095) / 4096, 512, 0, stream>>>(x_rows, x_cols, x_vals, nnz_x, curx, stage_x, nb);
        bucket_scatter<<<(n_e + 4095) / 4096, 512, 0, stream>>>(adj_rows, adj_cols, adj_vals, n_e, cura, stage_a, nb);

        // 5/6. fused fine-sort + row-gather consumers (block per bucket)
        consumer_xw<<<nb, 256, 0, stream>>>(bx, stage_x, W, xwh, N);
        consumer_adj<<<nb, 256, 0, stream>>>(ba, stage_a, xwh, out, N);
    } else {
        // Fallback: atomic scatter path (fp32 xw in ws)
        float* xw = (float*)ws;
        hipMemsetAsync(xw, 0, (size_t)out_size * sizeof(float), stream);
        hipMemsetAsync(out, 0, (size_t)out_size * sizeof(float), stream);
        long long t1 = (long long)nnz_x * DOUT;
        spmm_xw_atomic<<<(int)((t1 + 255) / 256), 256, 0, stream>>>(x_vals, x_rows, x_cols, W, xw, nnz_x);
        long long t2 = (long long)n_e * DOUT;
        spmm_adj_atomic<<<(int)((t2 + 255) / 256), 256, 0, stream>>>(adj_vals, adj_rows, adj_cols, xw, out, n_e);
        relu_kernel<<<(out_size / 4 + 255) / 256, 256, 0, stream>>>((float4*)out, out_size / 4);
    }
}

// Round 5
// 326.571 us; speedup vs baseline: 3.4640x; 1.2692x over previous
//
#include <hip/hip_runtime.h>
#include <hip/hip_fp16.h>

// GraphConvolutionSparse forward. Coarse-bucket sort (128 rows/bucket) +
// consumers that fine-sort each bucket in LDS and register-accumulate rows.
// Round-5 change: consumers go 256->512 threads and CAP 8192->4096 so all
// 782 blocks are co-resident (occupancy 30%->~75%) to hide gather latency.
//
// Pipeline (7 dispatches):
//   1. memset coarse counters (8 KB)
//   2. hist_coarse: LDS-aggregated bucket histogram of both matrices
//   3. scan_nb: exclusive scan of buckets (grid=2), writes base+cursor
//   4. bucket_scatter x2: block-reserved scatter of packed (row_lo|col, val)
//   5. consumer_xw: block/bucket, LDS perm, wave-per-row; write xw fp16
//   6. consumer_adj: same over adjacency, gather xw fp16, fused relu

#define DOUT 128
#define RB 128            // rows per bucket
#define RB_BITS 7
#define NBMAX 1024        // max buckets (N <= 131072, matches 17-bit packing)
#define CAP 4096          // max payloads per bucket on the fast path
#define COLMASK 131071    // low 17 bits
#define CTH 512           // consumer threads
#define CWAVES 8

static inline size_t align_up(size_t x, size_t a) { return (x + a - 1) & ~(a - 1); }

__device__ inline int wave_incl_scan(int v, int lane) {
    #pragma unroll
    for (int off = 1; off < 64; off <<= 1) {
        int up = __shfl_up(v, off, 64);
        if (lane >= off) v += up;
    }
    return v;
}

// ---- 2. coarse histogram, both matrices, LDS-aggregated ----
__global__ __launch_bounds__(256) void hist_coarse(const int* __restrict__ xr, int nx,
                                                   const int* __restrict__ ar, int na,
                                                   int* __restrict__ cx, int* __restrict__ ca) {
    __shared__ int h[2 * NBMAX];
    for (int i = threadIdx.x; i < 2 * NBMAX; i += 256) h[i] = 0;
    __syncthreads();
    int base = blockIdx.x * 4096;
    int tot = nx + na;
    #pragma unroll
    for (int k = 0; k < 16; ++k) {
        int i = base + k * 256 + threadIdx.x;
        if (i < tot) {
            if (i < nx) atomicAdd(&h[xr[i] >> RB_BITS], 1);
            else        atomicAdd(&h[NBMAX + (ar[i - nx] >> RB_BITS)], 1);
        }
    }
    __syncthreads();
    for (int i = threadIdx.x; i < 2 * NBMAX; i += 256) {
        int c = h[i];
        if (c) {
            if (i < NBMAX) atomicAdd(&cx[i], c);
            else           atomicAdd(&ca[i - NBMAX], c);
        }
    }
}

// ---- 3. exclusive scan of nb (<=1024) bucket counts; grid=2 picks matrix ----
__global__ __launch_bounds__(1024) void scan_nb(const int* __restrict__ cx, const int* __restrict__ ca,
                                                int* __restrict__ bx, int* __restrict__ ba,
                                                int* __restrict__ curx, int* __restrict__ cura, int nb) {
    const int* c = blockIdx.x ? ca : cx;
    int* bs  = blockIdx.x ? ba : bx;
    int* cur = blockIdx.x ? cura : curx;
    __shared__ int wsum[16];
    int tid = threadIdx.x, lane = tid & 63, wid = tid >> 6;
    int v = (tid < nb) ? c[tid] : 0;
    int incl = wave_incl_scan(v, lane);
    if (lane == 63) wsum[wid] = incl;
    __syncthreads();
    if (tid < 16) {
        int s = wsum[tid];
        int is = s;
        #pragma unroll
        for (int off = 1; off < 16; off <<= 1) {
            int up = __shfl_up(is, off, 64);
            if (tid >= off) is += up;
        }
        wsum[tid] = is - s;
    }
    __syncthreads();
    int excl = incl - v + wsum[wid];
    if (tid < nb) { bs[tid] = excl; cur[tid] = excl; }
    if (tid == nb - 1) bs[nb] = excl + v;
}

// ---- 4. bucket scatter with block-aggregated reservations ----
__global__ __launch_bounds__(512) void bucket_scatter(const int* __restrict__ rows, const int* __restrict__ cols,
                                                      const float* __restrict__ vals, int n,
                                                      int* __restrict__ gcur, int2* __restrict__ stage, int nb) {
    __shared__ int h[NBMAX];
    __shared__ int bcur[NBMAX];
    for (int i = threadIdx.x; i < nb; i += 512) h[i] = 0;
    __syncthreads();
    int base = blockIdx.x * 4096;
    int rr[8]; int cc[8]; float vv[8];
    #pragma unroll
    for (int k = 0; k < 8; ++k) {
        int i = base + k * 512 + threadIdx.x;
        rr[k] = -1;
        if (i < n) {
            rr[k] = rows[i]; cc[k] = cols[i]; vv[k] = vals[i];
            atomicAdd(&h[rr[k] >> RB_BITS], 1);
        }
    }
    __syncthreads();
    for (int b = threadIdx.x; b < nb; b += 512) {
        int c = h[b];
        bcur[b] = c ? atomicAdd(&gcur[b], c) : 0;
    }
    __syncthreads();
    #pragma unroll
    for (int k = 0; k < 8; ++k) {
        if (rr[k] >= 0) {
            int b = rr[k] >> RB_BITS;
            int p = atomicAdd(&bcur[b], 1);
            stage[p] = make_int2(((rr[k] & (RB - 1)) << 17) | cc[k], __float_as_int(vv[k]));
        }
    }
}

// ---- 5/6. consumers: block per bucket, LDS perm, wave per row ----
__global__ __launch_bounds__(CTH) void consumer_xw(const int* __restrict__ bx, const int2* __restrict__ stage,
                                                   const float* __restrict__ W, __half2* __restrict__ xwh, int N) {
    __shared__ unsigned short perm[CAP];
    __shared__ int hoff[RB + 1];
    __shared__ int curs[RB];
    __shared__ int w0s;
    int b = blockIdx.x;
    int s = bx[b], e = bx[b + 1];
    int cnt = e - s;
    int tid = threadIdx.x, lane = tid & 63, wid = tid >> 6;
    bool fast = (cnt <= CAP);
    if (tid < RB) curs[tid] = 0;
    __syncthreads();
    if (fast) {
        for (int i = tid; i < cnt; i += CTH)
            atomicAdd(&curs[(stage[s + i].x >> 17) & (RB - 1)], 1);
    }
    __syncthreads();
    {   // exclusive scan of the 128 counts (first 2 waves)
        int v = (tid < RB) ? curs[tid] : 0;
        int incl = wave_incl_scan(v, lane);
        if (tid == 63) w0s = incl;
        __syncthreads();
        if (tid < RB) {
            int excl = incl - v + (wid == 1 ? w0s : 0);
            hoff[tid] = excl;
            curs[tid] = excl;
            if (tid == RB - 1) hoff[RB] = excl + v;
        }
        __syncthreads();
    }
    if (fast) {
        for (int i = tid; i < cnt; i += CTH) {
            int r = (stage[s + i].x >> 17) & (RB - 1);
            perm[atomicAdd(&curs[r], 1)] = (unsigned short)i;
        }
    }
    __syncthreads();
    int row0 = b << RB_BITS;
    for (int r = wid; r < RB; r += CWAVES) {
        int grow = row0 + r;
        if (grow >= N) continue;
        float ax = 0.f, ay = 0.f;
        if (fast) {
            int j = hoff[r], o1 = hoff[r + 1];
            for (; j + 1 < o1; j += 2) {
                int2 c0 = stage[s + perm[j]];
                int2 c1 = stage[s + perm[j + 1]];
                float2 w0 = ((const float2*)(W + ((size_t)(c0.x & COLMASK) << 7)))[lane];
                float2 w1 = ((const float2*)(W + ((size_t)(c1.x & COLMASK) << 7)))[lane];
                float v0 = __int_as_float(c0.y), v1 = __int_as_float(c1.y);
                ax += v0 * w0.x + v1 * w1.x;
                ay += v0 * w0.y + v1 * w1.y;
            }
            if (j < o1) {
                int2 c0 = stage[s + perm[j]];
                float2 w0 = ((const float2*)(W + ((size_t)(c0.x & COLMASK) << 7)))[lane];
                float v0 = __int_as_float(c0.y);
                ax += v0 * w0.x; ay += v0 * w0.y;
            }
        } else {
            for (int j = 0; j < cnt; ++j) {
                int2 c0 = stage[s + j];
                if (((c0.x >> 17) & (RB - 1)) == r) {
                    float2 w0 = ((const float2*)(W + ((size_t)(c0.x & COLMASK) << 7)))[lane];
                    float v0 = __int_as_float(c0.y);
                    ax += v0 * w0.x; ay += v0 * w0.y;
                }
            }
        }
        xwh[((size_t)grow << 6) + lane] = __float22half2_rn(make_float2(ax, ay));
    }
}

__global__ __launch_bounds__(CTH) void consumer_adj(const int* __restrict__ ba, const int2* __restrict__ stage,
                                                    const __half2* __restrict__ xwh, float* __restrict__ out, int N) {
    __shared__ unsigned short perm[CAP];
    __shared__ int hoff[RB + 1];
    __shared__ int curs[RB];
    __shared__ int w0s;
    int b = blockIdx.x;
    int s = ba[b], e = ba[b + 1];
    int cnt = e - s;
    int tid = threadIdx.x, lane = tid & 63, wid = tid >> 6;
    bool fast = (cnt <= CAP);
    if (tid < RB) curs[tid] = 0;
    __syncthreads();
    if (fast) {
        for (int i = tid; i < cnt; i += CTH)
            atomicAdd(&curs[(stage[s + i].x >> 17) & (RB - 1)], 1);
    }
    __syncthreads();
    {
        int v = (tid < RB) ? curs[tid] : 0;
        int incl = wave_incl_scan(v, lane);
        if (tid == 63) w0s = incl;
        __syncthreads();
        if (tid < RB) {
            int excl = incl - v + (wid == 1 ? w0s : 0);
            hoff[tid] = excl;
            curs[tid] = excl;
            if (tid == RB - 1) hoff[RB] = excl + v;
        }
        __syncthreads();
    }
    if (fast) {
        for (int i = tid; i < cnt; i += CTH) {
            int r = (stage[s + i].x >> 17) & (RB - 1);
            perm[atomicAdd(&curs[r], 1)] = (unsigned short)i;
        }
    }
    __syncthreads();
    int row0 = b << RB_BITS;
    for (int r = wid; r < RB; r += CWAVES) {
        int grow = row0 + r;
        if (grow >= N) continue;
        float ax = 0.f, ay = 0.f;
        if (fast) {
            int j = hoff[r], o1 = hoff[r + 1];
            for (; j + 1 < o1; j += 2) {
                int2 c0 = stage[s + perm[j]];
                int2 c1 = stage[s + perm[j + 1]];
                float2 h0 = __half22float2(xwh[((size_t)(c0.x & COLMASK) << 6) + lane]);
                float2 h1 = __half22float2(xwh[((size_t)(c1.x & COLMASK) << 6) + lane]);
                float v0 = __int_as_float(c0.y), v1 = __int_as_float(c1.y);
                ax += v0 * h0.x + v1 * h1.x;
                ay += v0 * h0.y + v1 * h1.y;
            }
            if (j < o1) {
                int2 c0 = stage[s + perm[j]];
                float2 h0 = __half22float2(xwh[((size_t)(c0.x & COLMASK) << 6) + lane]);
                float v0 = __int_as_float(c0.y);
                ax += v0 * h0.x; ay += v0 * h0.y;
            }
        } else {
            for (int j = 0; j < cnt; ++j) {
                int2 c0 = stage[s + j];
                if (((c0.x >> 17) & (RB - 1)) == r) {
                    float2 h0 = __half22float2(xwh[((size_t)(c0.x & COLMASK) << 6) + lane]);
                    float v0 = __int_as_float(c0.y);
                    ax += v0 * h0.x; ay += v0 * h0.y;
                }
            }
        }
        ((float2*)(out + (size_t)grow * DOUT))[lane] = make_float2(fmaxf(ax, 0.f), fmaxf(ay, 0.f));
    }
}

// ---- fallback (atomic scatter) for oversized N / undersized ws ----
__global__ void spmm_xw_atomic(const float* __restrict__ x_vals, const int* __restrict__ x_rows,
                               const int* __restrict__ x_cols, const float* __restrict__ W,
                               float* __restrict__ xw, int nnz) {
    long long t = (long long)blockIdx.x * blockDim.x + threadIdx.x;
    int i = (int)(t >> 7), d = (int)(t & 127);
    if (i >= nnz) return;
    atomicAdd(&xw[(long long)x_rows[i] * DOUT + d], x_vals[i] * W[(long long)x_cols[i] * DOUT + d]);
}
__global__ void spmm_adj_atomic(const float* __restrict__ adj_vals, const int* __restrict__ adj_rows,
                                const int* __restrict__ adj_cols, const float* __restrict__ xw,
                                float* __restrict__ out, int n_e) {
    long long t = (long long)blockIdx.x * blockDim.x + threadIdx.x;
    int e = (int)(t >> 7), d = (int)(t & 127);
    if (e >= n_e) return;
    atomicAdd(&out[(long long)adj_rows[e] * DOUT + d], adj_vals[e] * xw[(long long)adj_cols[e] * DOUT + d]);
}
__global__ void relu_kernel(float4* __restrict__ out, int n4) {
    int i = blockIdx.x * blockDim.x + threadIdx.x;
    if (i >= n4) return;
    float4 v = out[i];
    v.x = fmaxf(v.x, 0.f); v.y = fmaxf(v.y, 0.f);
    v.z = fmaxf(v.z, 0.f); v.w = fmaxf(v.w, 0.f);
    out[i] = v;
}

extern "C" void kernel_launch(void* const* d_in, const int* in_sizes, int n_in,
                              void* d_out, int out_size, void* d_ws, size_t ws_size,
                              hipStream_t stream) {
    const float* x_vals   = (const float*)d_in[0];
    const int*   x_rows   = (const int*)d_in[1];
    const int*   x_cols   = (const int*)d_in[2];
    const float* adj_vals = (const float*)d_in[3];
    const int*   adj_rows = (const int*)d_in[4];
    const int*   adj_cols = (const int*)d_in[5];
    const float* W        = (const float*)d_in[6];
    float* out = (float*)d_out;

    const int nnz_x = in_sizes[0];
    const int n_e   = in_sizes[3];
    const int N     = out_size / DOUT;
    const int nb    = (N + RB - 1) / RB;

    // Workspace layout
    char* ws = (char*)d_ws;
    size_t off = 0;
    size_t xw_off    = off; off = align_up(off + (size_t)N * DOUT * sizeof(__half), 128);
    size_t cx_off    = off; off += (size_t)NBMAX * sizeof(int);       // cx | ca adjacent
    size_t ca_off    = off; off = align_up(off + (size_t)NBMAX * sizeof(int), 128);
    size_t bx_off    = off; off = align_up(off + (size_t)(NBMAX + 1) * sizeof(int), 128);
    size_t baoff     = off; off = align_up(off + (size_t)(NBMAX + 1) * sizeof(int), 128);
    size_t curx_off  = off; off = align_up(off + (size_t)NBMAX * sizeof(int), 128);
    size_t cura_off  = off; off = align_up(off + (size_t)NBMAX * sizeof(int), 128);
    size_t sx_off    = off; off = align_up(off + (size_t)nnz_x * sizeof(int2), 128);
    size_t sa_off    = off; off = align_up(off + (size_t)n_e * sizeof(int2), 128);
    size_t needed = off;

    if (ws_size >= needed && nb <= NBMAX && N <= (COLMASK + 1)) {
        __half2* xwh  = (__half2*)(ws + xw_off);
        int*  cx      = (int*)(ws + cx_off);
        int*  ca      = (int*)(ws + ca_off);
        int*  bx      = (int*)(ws + bx_off);
        int*  ba      = (int*)(ws + baoff);
        int*  curx    = (int*)(ws + curx_off);
        int*  cura    = (int*)(ws + cura_off);
        int2* stage_x = (int2*)(ws + sx_off);
        int2* stage_a = (int2*)(ws + sa_off);

        // 1. zero coarse counters (adjacent -> one memset)
        hipMemsetAsync(cx, 0, 2 * (size_t)NBMAX * sizeof(int), stream);

        // 2. coarse histogram of both matrices
        int tot = nnz_x + n_e;
        hist_coarse<<<(tot + 4095) / 4096, 256, 0, stream>>>(x_rows, nnz_x, adj_rows, n_e, cx, ca);

        // 3. bucket scan (grid=2: X, A)
        scan_nb<<<2, 1024, 0, stream>>>(cx, ca, bx, ba, curx, cura, nb);

        // 4. bucket scatters
        bucket_scatter<<<(nnz_x + 4095) / 4096, 512, 0, stream>>>(x_rows, x_cols, x_vals, nnz_x, curx, stage_x, nb);
        bucket_scatter<<<(n_e + 4095) / 4096, 512, 0, stream>>>(adj_rows, adj_cols, adj_vals, n_e, cura, stage_a, nb);

        // 5/6. fused fine-sort + row-gather consumers (block per bucket,
        // 512 threads: all nb blocks co-resident, 16 rows per wave)
        consumer_xw<<<nb, CTH, 0, stream>>>(bx, stage_x, W, xwh, N);
        consumer_adj<<<nb, CTH, 0, stream>>>(ba, stage_a, xwh, out, N);
    } else {
        // Fallback: atomic scatter path (fp32 xw in ws)
        float* xw = (float*)ws;
        hipMemsetAsync(xw, 0, (size_t)out_size * sizeof(float), stream);
        hipMemsetAsync(out, 0, (size_t)out_size * sizeof(float), stream);
        long long t1 = (long long)nnz_x * DOUT;
        spmm_xw_atomic<<<(int)((t1 + 255) / 256), 256, 0, stream>>>(x_vals, x_rows, x_cols, W, xw, nnz_x);
        long long t2 = (long long)n_e * DOUT;
        spmm_adj_atomic<<<(int)((t2 + 255) / 256), 256, 0, stream>>>(adj_vals, adj_rows, adj_cols, xw, out, n_e);
        relu_kernel<<<(out_size / 4 + 255) / 256, 256, 0, stream>>>((float4*)out, out_size / 4);
    }
}

// Round 6
// 242.550 us; speedup vs baseline: 4.6639x; 1.3464x over previous
//
#include <hip/hip_runtime.h>
#include <hip/hip_fp16.h>

// GraphConvolutionSparse forward. Coarse-bucket sort (64 rows/bucket) +
// consumers that fine-sort each bucket into an LDS payload array and
// register-accumulate rows with unroll-4 independent gathers.
//
// Round-6 changes vs round-5:
//   - RB 128->64, CTH 512->256: nb ~1563 blocks -> ~6 blocks/CU, occupancy cap ~76%
//   - rank phase scatters payloads into sorted LDS array sp[] (kills the
//     perm->stage L2 hop in the inner loop; chain is now LDS -> global)
//   - inner loop unroll-4: 4 independent xwh/W gathers in flight per wave
//   - both bucket scatters fused into one dispatch (block-range split)
//
// Pipeline (6 dispatches): memset, hist_coarse, scan_nb, bucket_scatter2,
// consumer_xw, consumer_adj.

#define DOUT 128
#define RB 64             // rows per bucket
#define RB_BITS 6
#define NBMAX 2048        // max buckets (N <= 131072, matches 17-bit packing)
#define CAP 2048          // max payloads per bucket on the fast path
#define COLMASK 131071    // low 17 bits
#define CTH 256           // consumer threads
#define CWAVES 4

static inline size_t align_up(size_t x, size_t a) { return (x + a - 1) & ~(a - 1); }

__device__ inline int wave_incl_scan(int v, int lane) {
    #pragma unroll
    for (int off = 1; off < 64; off <<= 1) {
        int up = __shfl_up(v, off, 64);
        if (lane >= off) v += up;
    }
    return v;
}

// ---- 2. coarse histogram, both matrices, LDS-aggregated ----
__global__ __launch_bounds__(256) void hist_coarse(const int* __restrict__ xr, int nx,
                                                   const int* __restrict__ ar, int na,
                                                   int* __restrict__ cx, int* __restrict__ ca) {
    __shared__ int h[2 * NBMAX];
    for (int i = threadIdx.x; i < 2 * NBMAX; i += 256) h[i] = 0;
    __syncthreads();
    int base = blockIdx.x * 4096;
    int tot = nx + na;
    #pragma unroll
    for (int k = 0; k < 16; ++k) {
        int i = base + k * 256 + threadIdx.x;
        if (i < tot) {
            if (i < nx) atomicAdd(&h[xr[i] >> RB_BITS], 1);
            else        atomicAdd(&h[NBMAX + (ar[i - nx] >> RB_BITS)], 1);
        }
    }
    __syncthreads();
    for (int i = threadIdx.x; i < 2 * NBMAX; i += 256) {
        int c = h[i];
        if (c) {
            if (i < NBMAX) atomicAdd(&cx[i], c);
            else           atomicAdd(&ca[i - NBMAX], c);
        }
    }
}

// ---- 3. exclusive scan of nb bucket counts (carry loop); grid=2 picks matrix ----
__global__ __launch_bounds__(1024) void scan_nb(const int* __restrict__ cx, const int* __restrict__ ca,
                                                int* __restrict__ bx, int* __restrict__ ba,
                                                int* __restrict__ curx, int* __restrict__ cura, int nb) {
    const int* c = blockIdx.x ? ca : cx;
    int* bs  = blockIdx.x ? ba : bx;
    int* cur = blockIdx.x ? cura : curx;
    __shared__ int wsum[16];
    __shared__ int woff[16];
    __shared__ int carry_s, chunk_tot;
    int tid = threadIdx.x, lane = tid & 63, wid = tid >> 6;
    if (tid == 0) carry_s = 0;
    __syncthreads();
    for (int base = 0; base < nb; base += 1024) {
        int i = base + tid;
        int v = (i < nb) ? c[i] : 0;
        int incl = wave_incl_scan(v, lane);
        if (lane == 63) wsum[wid] = incl;
        __syncthreads();
        if (wid == 0 && lane < 16) {
            int s = wsum[lane];
            int is = s;
            #pragma unroll
            for (int off = 1; off < 16; off <<= 1) {
                int up = __shfl_up(is, off, 64);
                if (lane >= off) is += up;
            }
            woff[lane] = is - s;
            if (lane == 15) chunk_tot = is;
        }
        __syncthreads();
        int excl = incl - v + woff[wid] + carry_s;
        if (i < nb) { bs[i] = excl; cur[i] = excl; }
        __syncthreads();
        if (tid == 0) carry_s += chunk_tot;
        __syncthreads();
    }
    if (tid == 0) bs[nb] = carry_s;
}

// ---- 4. fused bucket scatter (X blocks then A blocks) ----
__global__ __launch_bounds__(512) void bucket_scatter2(const int* __restrict__ xr, const int* __restrict__ xc,
                                                       const float* __restrict__ xv, int nx,
                                                       const int* __restrict__ ar, const int* __restrict__ ac,
                                                       const float* __restrict__ av, int na,
                                                       int* __restrict__ curx, int* __restrict__ cura,
                                                       int2* __restrict__ stx, int2* __restrict__ sta,
                                                       int nb, int nblk_x) {
    const int* rows; const int* cols; const float* vals; int n; int* gcur; int2* stage; int base;
    if (blockIdx.x < nblk_x) {
        rows = xr; cols = xc; vals = xv; n = nx; gcur = curx; stage = stx;
        base = blockIdx.x * 4096;
    } else {
        rows = ar; cols = ac; vals = av; n = na; gcur = cura; stage = sta;
        base = (blockIdx.x - nblk_x) * 4096;
    }
    __shared__ int h[NBMAX];
    __shared__ int bcur[NBMAX];
    for (int i = threadIdx.x; i < nb; i += 512) h[i] = 0;
    __syncthreads();
    int rr[8]; int cc[8]; float vv[8];
    #pragma unroll
    for (int k = 0; k < 8; ++k) {
        int i = base + k * 512 + threadIdx.x;
        rr[k] = -1;
        if (i < n) {
            rr[k] = rows[i]; cc[k] = cols[i]; vv[k] = vals[i];
            atomicAdd(&h[rr[k] >> RB_BITS], 1);
        }
    }
    __syncthreads();
    for (int b = threadIdx.x; b < nb; b += 512) {
        int c = h[b];
        bcur[b] = c ? atomicAdd(&gcur[b], c) : 0;
    }
    __syncthreads();
    #pragma unroll
    for (int k = 0; k < 8; ++k) {
        if (rr[k] >= 0) {
            int b = rr[k] >> RB_BITS;
            int p = atomicAdd(&bcur[b], 1);
            stage[p] = make_int2(((rr[k] & (RB - 1)) << 17) | cc[k], __float_as_int(vv[k]));
        }
    }
}

// ---- 5/6. consumers: block per bucket, sorted payloads in LDS, wave per row ----
__global__ __launch_bounds__(CTH) void consumer_xw(const int* __restrict__ bx, const int2* __restrict__ stage,
                                                   const float* __restrict__ W, __half2* __restrict__ xwh, int N) {
    __shared__ int2 sp[CAP];
    __shared__ int hoff[RB + 1];
    __shared__ int curs[RB];
    int b = blockIdx.x;
    int s = bx[b], e = bx[b + 1];
    int cnt = e - s;
    int tid = threadIdx.x, lane = tid & 63, wid = tid >> 6;
    bool fast = (cnt <= CAP);
    if (tid < RB) curs[tid] = 0;
    __syncthreads();
    if (fast) {
        for (int i = tid; i < cnt; i += CTH)
            atomicAdd(&curs[(stage[s + i].x >> 17) & (RB - 1)], 1);
    }
    __syncthreads();
    if (wid == 0) {   // one wave scans the 64 counts
        int v = curs[lane];
        int incl = wave_incl_scan(v, lane);
        int excl = incl - v;
        hoff[lane] = excl;
        curs[lane] = excl;
        if (lane == 63) hoff[RB] = incl;
    }
    __syncthreads();
    if (fast) {
        for (int i = tid; i < cnt; i += CTH) {
            int2 p = stage[s + i];
            int r = (p.x >> 17) & (RB - 1);
            sp[atomicAdd(&curs[r], 1)] = p;
        }
    }
    __syncthreads();
    int row0 = b << RB_BITS;
    #pragma unroll 1
    for (int rr = 0; rr < RB / CWAVES; ++rr) {
        int r = wid + rr * CWAVES;
        int grow = row0 + r;
        if (grow >= N) continue;
        float ax = 0.f, ay = 0.f;
        if (fast) {
            int j = hoff[r], o1 = hoff[r + 1];
            for (; j + 3 < o1; j += 4) {
                int2 c0 = sp[j], c1 = sp[j + 1], c2 = sp[j + 2], c3 = sp[j + 3];
                float2 w0 = ((const float2*)(W + ((size_t)(c0.x & COLMASK) << 7)))[lane];
                float2 w1 = ((const float2*)(W + ((size_t)(c1.x & COLMASK) << 7)))[lane];
                float2 w2 = ((const float2*)(W + ((size_t)(c2.x & COLMASK) << 7)))[lane];
                float2 w3 = ((const float2*)(W + ((size_t)(c3.x & COLMASK) << 7)))[lane];
                float v0 = __int_as_float(c0.y), v1 = __int_as_float(c1.y);
                float v2 = __int_as_float(c2.y), v3 = __int_as_float(c3.y);
                ax += v0 * w0.x + v1 * w1.x + v2 * w2.x + v3 * w3.x;
                ay += v0 * w0.y + v1 * w1.y + v2 * w2.y + v3 * w3.y;
            }
            for (; j < o1; ++j) {
                int2 c0 = sp[j];
                float2 w0 = ((const float2*)(W + ((size_t)(c0.x & COLMASK) << 7)))[lane];
                float v0 = __int_as_float(c0.y);
                ax += v0 * w0.x; ay += v0 * w0.y;
            }
        } else {
            for (int j = 0; j < cnt; ++j) {
                int2 c0 = stage[s + j];
                if (((c0.x >> 17) & (RB - 1)) == r) {
                    float2 w0 = ((const float2*)(W + ((size_t)(c0.x & COLMASK) << 7)))[lane];
                    float v0 = __int_as_float(c0.y);
                    ax += v0 * w0.x; ay += v0 * w0.y;
                }
            }
        }
        xwh[((size_t)grow << 6) + lane] = __float22half2_rn(make_float2(ax, ay));
    }
}

__global__ __launch_bounds__(CTH) void consumer_adj(const int* __restrict__ ba, const int2* __restrict__ stage,
                                                    const __half2* __restrict__ xwh, float* __restrict__ out, int N) {
    __shared__ int2 sp[CAP];
    __shared__ int hoff[RB + 1];
    __shared__ int curs[RB];
    int b = blockIdx.x;
    int s = ba[b], e = ba[b + 1];
    int cnt = e - s;
    int tid = threadIdx.x, lane = tid & 63, wid = tid >> 6;
    bool fast = (cnt <= CAP);
    if (tid < RB) curs[tid] = 0;
    __syncthreads();
    if (fast) {
        for (int i = tid; i < cnt; i += CTH)
            atomicAdd(&curs[(stage[s + i].x >> 17) & (RB - 1)], 1);
    }
    __syncthreads();
    if (wid == 0) {
        int v = curs[lane];
        int incl = wave_incl_scan(v, lane);
        int excl = incl - v;
        hoff[lane] = excl;
        curs[lane] = excl;
        if (lane == 63) hoff[RB] = incl;
    }
    __syncthreads();
    if (fast) {
        for (int i = tid; i < cnt; i += CTH) {
            int2 p = stage[s + i];
            int r = (p.x >> 17) & (RB - 1);
            sp[atomicAdd(&curs[r], 1)] = p;
        }
    }
    __syncthreads();
    int row0 = b << RB_BITS;
    #pragma unroll 1
    for (int rr = 0; rr < RB / CWAVES; ++rr) {
        int r = wid + rr * CWAVES;
        int grow = row0 + r;
        if (grow >= N) continue;
        float ax = 0.f, ay = 0.f;
        if (fast) {
            int j = hoff[r], o1 = hoff[r + 1];
            for (; j + 3 < o1; j += 4) {
                int2 c0 = sp[j], c1 = sp[j + 1], c2 = sp[j + 2], c3 = sp[j + 3];
                float2 h0 = __half22float2(xwh[((size_t)(c0.x & COLMASK) << 6) + lane]);
                float2 h1 = __half22float2(xwh[((size_t)(c1.x & COLMASK) << 6) + lane]);
                float2 h2 = __half22float2(xwh[((size_t)(c2.x & COLMASK) << 6) + lane]);
                float2 h3 = __half22float2(xwh[((size_t)(c3.x & COLMASK) << 6) + lane]);
                float v0 = __int_as_float(c0.y), v1 = __int_as_float(c1.y);
                float v2 = __int_as_float(c2.y), v3 = __int_as_float(c3.y);
                ax += v0 * h0.x + v1 * h1.x + v2 * h2.x + v3 * h3.x;
                ay += v0 * h0.y + v1 * h1.y + v2 * h2.y + v3 * h3.y;
            }
            for (; j < o1; ++j) {
                int2 c0 = sp[j];
                float2 h0 = __half22float2(xwh[((size_t)(c0.x & COLMASK) << 6) + lane]);
                float v0 = __int_as_float(c0.y);
                ax += v0 * h0.x; ay += v0 * h0.y;
            }
        } else {
            for (int j = 0; j < cnt; ++j) {
                int2 c0 = stage[s + j];
                if (((c0.x >> 17) & (RB - 1)) == r) {
                    float2 h0 = __half22float2(xwh[((size_t)(c0.x & COLMASK) << 6) + lane]);
                    float v0 = __int_as_float(c0.y);
                    ax += v0 * h0.x; ay += v0 * h0.y;
                }
            }
        }
        ((float2*)(out + (size_t)grow * DOUT))[lane] = make_float2(fmaxf(ax, 0.f), fmaxf(ay, 0.f));
    }
}

// ---- fallback (atomic scatter) for oversized N / undersized ws ----
__global__ void spmm_xw_atomic(const float* __restrict__ x_vals, const int* __restrict__ x_rows,
                               const int* __restrict__ x_cols, const float* __restrict__ W,
                               float* __restrict__ xw, int nnz) {
    long long t = (long long)blockIdx.x * blockDim.x + threadIdx.x;
    int i = (int)(t >> 7), d = (int)(t & 127);
    if (i >= nnz) return;
    atomicAdd(&xw[(long long)x_rows[i] * DOUT + d], x_vals[i] * W[(long long)x_cols[i] * DOUT + d]);
}
__global__ void spmm_adj_atomic(const float* __restrict__ adj_vals, const int* __restrict__ adj_rows,
                                const int* __restrict__ adj_cols, const float* __restrict__ xw,
                                float* __restrict__ out, int n_e) {
    long long t = (long long)blockIdx.x * blockDim.x + threadIdx.x;
    int e = (int)(t >> 7), d = (int)(t & 127);
    if (e >= n_e) return;
    atomicAdd(&out[(long long)adj_rows[e] * DOUT + d], adj_vals[e] * xw[(long long)adj_cols[e] * DOUT + d]);
}
__global__ void relu_kernel(float4* __restrict__ out, int n4) {
    int i = blockIdx.x * blockDim.x + threadIdx.x;
    if (i >= n4) return;
    float4 v = out[i];
    v.x = fmaxf(v.x, 0.f); v.y = fmaxf(v.y, 0.f);
    v.z = fmaxf(v.z, 0.f); v.w = fmaxf(v.w, 0.f);
    out[i] = v;
}

extern "C" void kernel_launch(void* const* d_in, const int* in_sizes, int n_in,
                              void* d_out, int out_size, void* d_ws, size_t ws_size,
                              hipStream_t stream) {
    const float* x_vals   = (const float*)d_in[0];
    const int*   x_rows   = (const int*)d_in[1];
    const int*   x_cols   = (const int*)d_in[2];
    const float* adj_vals = (const float*)d_in[3];
    const int*   adj_rows = (const int*)d_in[4];
    const int*   adj_cols = (const int*)d_in[5];
    const float* W        = (const float*)d_in[6];
    float* out = (float*)d_out;

    const int nnz_x = in_sizes[0];
    const int n_e   = in_sizes[3];
    const int N     = out_size / DOUT;
    const int nb    = (N + RB - 1) / RB;

    // Workspace layout
    char* ws = (char*)d_ws;
    size_t off = 0;
    size_t xw_off    = off; off = align_up(off + (size_t)N * DOUT * sizeof(__half), 128);
    size_t cx_off    = off; off += (size_t)NBMAX * sizeof(int);       // cx | ca adjacent
    size_t ca_off    = off; off = align_up(off + (size_t)NBMAX * sizeof(int), 128);
    size_t bx_off    = off; off = align_up(off + (size_t)(NBMAX + 1) * sizeof(int), 128);
    size_t baoff     = off; off = align_up(off + (size_t)(NBMAX + 1) * sizeof(int), 128);
    size_t curx_off  = off; off = align_up(off + (size_t)NBMAX * sizeof(int), 128);
    size_t cura_off  = off; off = align_up(off + (size_t)NBMAX * sizeof(int), 128);
    size_t sx_off    = off; off = align_up(off + (size_t)nnz_x * sizeof(int2), 128);
    size_t sa_off    = off; off = align_up(off + (size_t)n_e * sizeof(int2), 128);
    size_t needed = off;

    if (ws_size >= needed && nb <= NBMAX && N <= (COLMASK + 1)) {
        __half2* xwh  = (__half2*)(ws + xw_off);
        int*  cx      = (int*)(ws + cx_off);
        int*  ca      = (int*)(ws + ca_off);
        int*  bx      = (int*)(ws + bx_off);
        int*  ba      = (int*)(ws + baoff);
        int*  curx    = (int*)(ws + curx_off);
        int*  cura    = (int*)(ws + cura_off);
        int2* stage_x = (int2*)(ws + sx_off);
        int2* stage_a = (int2*)(ws + sa_off);

        // 1. zero coarse counters (adjacent -> one memset)
        hipMemsetAsync(cx, 0, 2 * (size_t)NBMAX * sizeof(int), stream);

        // 2. coarse histogram of both matrices
        int tot = nnz_x + n_e;
        hist_coarse<<<(tot + 4095) / 4096, 256, 0, stream>>>(x_rows, nnz_x, adj_rows, n_e, cx, ca);

        // 3. bucket scan (grid=2: X, A)
        scan_nb<<<2, 1024, 0, stream>>>(cx, ca, bx, ba, curx, cura, nb);

        // 4. fused bucket scatter
        int nblk_x = (nnz_x + 4095) / 4096;
        int nblk_a = (n_e + 4095) / 4096;
        bucket_scatter2<<<nblk_x + nblk_a, 512, 0, stream>>>(x_rows, x_cols, x_vals, nnz_x,
                                                             adj_rows, adj_cols, adj_vals, n_e,
                                                             curx, cura, stage_x, stage_a, nb, nblk_x);

        // 5/6. consumers (block per bucket, sorted payloads in LDS)
        consumer_xw<<<nb, CTH, 0, stream>>>(bx, stage_x, W, xwh, N);
        consumer_adj<<<nb, CTH, 0, stream>>>(ba, stage_a, xwh, out, N);
    } else {
        // Fallback: atomic scatter path (fp32 xw in ws)
        float* xw = (float*)ws;
        hipMemsetAsync(xw, 0, (size_t)out_size * sizeof(float), stream);
        hipMemsetAsync(out, 0, (size_t)out_size * sizeof(float), stream);
        long long t1 = (long long)nnz_x * DOUT;
        spmm_xw_atomic<<<(int)((t1 + 255) / 256), 256, 0, stream>>>(x_vals, x_rows, x_cols, W, xw, nnz_x);
        long long t2 = (long long)n_e * DOUT;
        spmm_adj_atomic<<<(int)((t2 + 255) / 256), 256, 0, stream>>>(adj_vals, adj_rows, adj_cols, xw, out, n_e);
        relu_kernel<<<(out_size / 4 + 255) / 256, 256, 0, stream>>>((float4*)out, out_size / 4);
    }
}